// Round 4
// baseline (815.773 us; speedup 1.0000x reference)
//
#include <hip/hip_runtime.h>
#include <hip/hip_fp16.h>

// GCN 2-layer + classifier, fp32 math, fp16 message buffers.
// R12: aggs rewritten EDGE-CENTRIC with LDS fp32 atomic accumulation.
//      R11 post-mortem: node-centric agg is latency-CHAIN bound (VALUBusy 15%,
//      HBM 8%, FETCH 30.8MB = ~5x replication of 6.4MB P1 across XCD L2s ->
//      many gathers pay ~900cyc HBM latency; register accumulator serializes
//      col->gather->fma per chunk). ds_add_f32 returns nothing -> iterations
//      fully independent -> throughput-bound. Block = 64 dst nodes, 512 thr,
//      8 thr/edge x 16B; dloc via 6-step binary search in LDS rps[65];
//      acc[64][65] pad spreads atomic banks; epilogue keeps W2/classifier
//      fusion (acc rows ARE the rbuf). ~33KB LDS -> 4 blocks/CU.
// R11 pipeline + 512-thr scatA/binB REVERTED (regressed: compiler emits
//      conservative vmcnt(0) around guarded prefetches).
// R10: (superseded in aggs) 8 lanes/node uint4 gathers.
// R9: gemm1 fused into hist kernel. P1 UNSCALED h=X@W1; source-side norm
//     applied in aggE1 as gathered weight wk=inv[src]. P2 pre-scaled.
// CSR-by-dst rebuilt per launch via radix partition, ZERO global atomics.
// Requires n < 65536 (u16 col). Here n=50000, E=800000.

#define FDIM 64
#define NCLS 16
#define TILE 2048
#define ANODE 64

// ---- partition pass 1: per-(tile,bucket) histogram + fused layer-1 GEMM ----
__global__ __launch_bounds__(256) void k_histgemm(const int* __restrict__ dst, int E,
                                                  int* __restrict__ H, int nblk,
                                                  const float* __restrict__ X,
                                                  const float* __restrict__ W,
                                                  __half* __restrict__ Yh, int n) {
    __shared__ float Ws[FDIM * FDIM];
    __shared__ int h[256];
    int t = threadIdx.x, blk = blockIdx.x;
    if (blk < nblk) {
        h[t] = 0;
        __syncthreads();
        int i0 = blk * TILE;
#pragma unroll
        for (int k = 0; k < TILE / 256; ++k) {
            int i = i0 + k * 256 + t;
            if (i < E) atomicAdd(&h[dst[i] >> 8], 1);
        }
        __syncthreads();
        H[blk * 256 + t] = h[t];   // coalesced
    } else {
        for (int i = t; i < FDIM * FDIM; i += 256) Ws[i] = W[i];
        __syncthreads();
        int idx = (blk - nblk) * 256 + t;
        int row = idx >> 2;
        int cg = (idx & 3) * 16;
        if (row >= n) return;
        const float4* xr = (const float4*)(X + (size_t)row * FDIM);
        float4 xv[16];
#pragma unroll
        for (int i = 0; i < 16; ++i) xv[i] = xr[i];
        float acc[16];
#pragma unroll
        for (int c = 0; c < 16; ++c) acc[c] = 0.f;
#pragma unroll
        for (int i = 0; i < 16; ++i) {
            float xs[4] = {xv[i].x, xv[i].y, xv[i].z, xv[i].w};
#pragma unroll
            for (int j = 0; j < 4; ++j) {
                float xk = xs[j];
                const float* wr = &Ws[(i * 4 + j) * FDIM + cg];
#pragma unroll
                for (int c = 0; c < 16; ++c) acc[c] += xk * wr[c];
            }
        }
        unsigned u[8];
#pragma unroll
        for (int i = 0; i < 8; ++i) {
            __half2 hp = __floats2half2_rn(acc[2 * i], acc[2 * i + 1]);
            u[i] = *(unsigned*)&hp;
        }
        uint4* yo = (uint4*)(Yh + (size_t)row * FDIM + cg);
        yo[0] = make_uint4(u[0], u[1], u[2], u[3]);
        yo[1] = make_uint4(u[4], u[5], u[6], u[7]);
    }
}

// ---- partition pass 2: per-bucket exclusive scan across tiles ----
__global__ __launch_bounds__(512) void k_scanH(int* __restrict__ H, int nblk, int* __restrict__ btot) {
    __shared__ int s[512];
    int t = threadIdx.x, b = blockIdx.x;
    int v = (t < nblk) ? H[t * 256 + b] : 0;
    s[t] = v;
    __syncthreads();
    for (int off = 1; off < 512; off <<= 1) {
        int add = (t >= off) ? s[t - off] : 0;
        __syncthreads();
        s[t] += add;
        __syncthreads();
    }
    if (t < nblk) H[t * 256 + b] = s[t] - v;  // exclusive within bucket
    if (t == 511) btot[b] = s[511];
}

// ---- partition pass 3: scatter packed records into bucket regions ----
__global__ __launch_bounds__(256) void k_scatA(const int* __restrict__ src, const int* __restrict__ dst,
                                               int E, const int* __restrict__ H,
                                               const int* __restrict__ btot, int nb,
                                               unsigned* __restrict__ tmp) {
    __shared__ int s[256];
    __shared__ int Hb[256];
    __shared__ int c2[256];
    int t = threadIdx.x, blk = blockIdx.x;
    int v = (t < nb) ? btot[t] : 0;
    s[t] = v;
    __syncthreads();
    for (int off = 1; off < 256; off <<= 1) {
        int add = (t >= off) ? s[t - off] : 0;
        __syncthreads();
        s[t] += add;
        __syncthreads();
    }
    Hb[t] = (s[t] - v) + H[blk * 256 + t];   // bucket base + tile offset
    c2[t] = 0;
    __syncthreads();
    int i0 = blk * TILE;
#pragma unroll
    for (int k = 0; k < TILE / 256; ++k) {
        int i = i0 + k * 256 + t;
        if (i < E) {
            int sv = src[i], d = dst[i];
            int b = d >> 8;
            unsigned rec = ((unsigned)(d & 255) << 16) | (unsigned)sv;
            int pos = Hb[b] + atomicAdd(&c2[b], 1);
            tmp[pos] = rec;
        }
    }
}

// ---- per-bucket CSR finalize: row_ptr, inv, coalesced u16 col ----
#define COLCAP 8192
__global__ __launch_bounds__(256) void k_binB(const unsigned* __restrict__ tmp,
                                              const int* __restrict__ btot, int nb,
                                              int n, int E, int* __restrict__ row_ptr,
                                              float* __restrict__ inv,
                                              unsigned short* __restrict__ col) {
    __shared__ int dcnt[256], s[256], cur[256];
    __shared__ unsigned short colbuf[COLCAP];
    int t = threadIdx.x, b = blockIdx.x;
    int v = (t < nb) ? btot[t] : 0;
    s[t] = v;
    __syncthreads();
    for (int off = 1; off < 256; off <<= 1) {
        int add = (t >= off) ? s[t - off] : 0;
        __syncthreads();
        s[t] += add;
        __syncthreads();
    }
    __shared__ int baseS;
    if (t == b) baseS = s[t] - v;
    dcnt[t] = 0;
    __syncthreads();
    int base = baseS;
    int cntE = btot[b];
    int node0 = b << 8;
    int nn = min(256, n - node0);
    for (int i = t; i < cntE; i += 256) atomicAdd(&dcnt[tmp[base + i] >> 16], 1);
    __syncthreads();
    int deg = dcnt[t];
    s[t] = deg;
    __syncthreads();
    for (int off = 1; off < 256; off <<= 1) {
        int add = (t >= off) ? s[t - off] : 0;
        __syncthreads();
        s[t] += add;
        __syncthreads();
    }
    int excl = s[t] - deg;
    if (t < nn) {
        row_ptr[node0 + t] = base + excl;
        inv[node0 + t] = rsqrtf((float)(deg + 1));
    }
    if (b == 0 && t == 0) row_ptr[n] = E;
    cur[t] = excl;
    __syncthreads();
    for (int i = t; i < cntE; i += 256) {
        unsigned r = tmp[base + i];
        int pos = atomicAdd(&cur[r >> 16], 1);
        unsigned short vv = (unsigned short)(r & 0xFFFFu);
        if (pos < COLCAP) colbuf[pos] = vv;
        else col[base + pos] = vv;   // overflow fallback
    }
    __syncthreads();
    int lim = min(cntE, COLCAP);
    for (int i = t; i < lim; i += 256) col[base + i] = colbuf[i];
}

__device__ __forceinline__ void unpack8(const uint4& q, float* f) {
    float2 f0 = __half22float2(*(const __half2*)&q.x);
    float2 f1 = __half22float2(*(const __half2*)&q.y);
    float2 f2 = __half22float2(*(const __half2*)&q.z);
    float2 f3 = __half22float2(*(const __half2*)&q.w);
    f[0] = f0.x; f[1] = f0.y; f[2] = f1.x; f[3] = f1.y;
    f[4] = f2.x; f[5] = f2.y; f[6] = f3.x; f[7] = f3.y;
}

// ---- agg layer 1, EDGE-CENTRIC + fused W2 GEMM -> P2 (fp16, pre-scaled) ----
// Block = 64 dst nodes, 512 threads. Edge range [row_ptr[b*64], row_ptr[b*64+64])
// is contiguous (CSR by dst). Thread = (edge-slot t>>3, feature-octet t&7).
// acc[64][65] fp32 in LDS; ds_add_f32 atomics -> NO serial dependency chain.
// dloc via 6-step binary search in rps[65]. Epilogue: r=relu(iv*(acc+iv*self)+b)
// in-place, then W2 GEMM (thread = node x octet), write P2 = fp16(iv*(r@W2)).
__global__ __launch_bounds__(512) void k_aggE1(const __half* __restrict__ Ph, const float* __restrict__ inv,
                                               const int* __restrict__ row_ptr,
                                               const unsigned short* __restrict__ col,
                                               const float* __restrict__ bias,
                                               const float* __restrict__ W2,
                                               __half* __restrict__ P2, int n) {
    __shared__ float acc[ANODE][FDIM + 1];
    __shared__ float W2s[FDIM * FDIM];
    __shared__ int rps[ANODE + 1];
    __shared__ float ivS[ANODE];
    int t = threadIdx.x;
    int node0 = blockIdx.x * ANODE;
    for (int i = t; i < FDIM * FDIM; i += 512) W2s[i] = W2[i];   // done by phase B
    if (t <= ANODE) rps[t] = row_ptr[min(node0 + t, n)];
    if (t < ANODE) ivS[t] = (node0 + t < n) ? inv[node0 + t] : 0.f;
    for (int i = t; i < ANODE * (FDIM + 1); i += 512) ((float*)acc)[i] = 0.f;
    __syncthreads();
    int sB = rps[0], eB = rps[ANODE];
    int fl = t & 7;
    const uint4* Pq = (const uint4*)Ph;
    for (int j = sB + (t >> 3); j < eB; j += 64) {
        int sv = col[j];
        uint4 q = Pq[sv * 8 + fl];
        float wk = inv[sv];
        int lo = 0;   // binary search: rps[lo] <= j < rps[lo+1]
#pragma unroll
        for (int st = 32; st >= 1; st >>= 1)
            if (rps[lo + st] <= j) lo += st;
        float f[8];
        unpack8(q, f);
        float* ar = acc[lo] + fl * 8;
#pragma unroll
        for (int i = 0; i < 8; ++i) atomicAdd(&ar[i], wk * f[i]);
    }
    __syncthreads();
    // epilogue: each (node, octet) element owned by exactly one thread
    int nl = t >> 3;
    int node = node0 + nl;
    int nodeC = min(node, n - 1);
    float iv = ivS[nl];
    uint4 selfq = Pq[nodeC * 8 + fl];
    float sf[8];
    unpack8(selfq, sf);
    float4 bb0 = ((const float4*)bias)[fl * 2];
    float4 bb1 = ((const float4*)bias)[fl * 2 + 1];
    float bbv[8] = {bb0.x, bb0.y, bb0.z, bb0.w, bb1.x, bb1.y, bb1.z, bb1.w};
    float* ar = acc[nl] + fl * 8;
#pragma unroll
    for (int i = 0; i < 8; ++i)
        ar[i] = fmaxf(fmaf(iv, ar[i] + iv * sf[i], bbv[i]), 0.f);
    __syncthreads();
    // phase B: W2 GEMM, thread = (node nl, octet fl)
    float o[8];
#pragma unroll
    for (int i = 0; i < 8; ++i) o[i] = 0.f;
    const float* rr = acc[nl];
#pragma unroll
    for (int i = 0; i < FDIM; ++i) {
        float xk = rr[i];
        const float* wv = &W2s[i * FDIM + fl * 8];
#pragma unroll
        for (int c = 0; c < 8; ++c) o[c] = fmaf(xk, wv[c], o[c]);
    }
    if (node < n) {
        unsigned u[4];
#pragma unroll
        for (int i = 0; i < 4; ++i) {
            __half2 hp = __floats2half2_rn(o[2 * i] * iv, o[2 * i + 1] * iv);
            u[i] = *(unsigned*)&hp;
        }
        ((uint4*)P2)[(size_t)node * 8 + fl] = make_uint4(u[0], u[1], u[2], u[3]);
    }
}

// ---- agg layer 2, EDGE-CENTRIC + fused classifier (P2 pre-scaled) ----
__global__ __launch_bounds__(512) void k_aggE2(const __half* __restrict__ Ph, const float* __restrict__ inv,
                                               const int* __restrict__ row_ptr,
                                               const unsigned short* __restrict__ col,
                                               const float* __restrict__ bias,
                                               const float* __restrict__ Wc, const float* __restrict__ bc,
                                               float* __restrict__ out, int n) {
    __shared__ float acc[ANODE][FDIM + 1];
    __shared__ float WcT[NCLS][FDIM + 1];   // transposed + padded (bank spread)
    __shared__ int rps[ANODE + 1];
    __shared__ float ivS[ANODE];
    int t = threadIdx.x;
    int node0 = blockIdx.x * ANODE;
    for (int i = t; i < FDIM * NCLS; i += 512) {
        int c = i & 15, ff = i >> 4;
        WcT[c][ff] = Wc[i];
    }
    if (t <= ANODE) rps[t] = row_ptr[min(node0 + t, n)];
    if (t < ANODE) ivS[t] = (node0 + t < n) ? inv[node0 + t] : 0.f;
    for (int i = t; i < ANODE * (FDIM + 1); i += 512) ((float*)acc)[i] = 0.f;
    __syncthreads();
    int sB = rps[0], eB = rps[ANODE];
    int fl = t & 7;
    const uint4* Pq = (const uint4*)Ph;
    for (int j = sB + (t >> 3); j < eB; j += 64) {
        int sv = col[j];
        uint4 q = Pq[sv * 8 + fl];
        int lo = 0;
#pragma unroll
        for (int st = 32; st >= 1; st >>= 1)
            if (rps[lo + st] <= j) lo += st;
        float f[8];
        unpack8(q, f);
        float* ar = acc[lo] + fl * 8;
#pragma unroll
        for (int i = 0; i < 8; ++i) atomicAdd(&ar[i], f[i]);
    }
    __syncthreads();
    int nl = t >> 3;
    int node = node0 + nl;
    int nodeC = min(node, n - 1);
    float iv = ivS[nl];
    uint4 selfq = Pq[nodeC * 8 + fl];
    float sf[8];
    unpack8(selfq, sf);
    float4 bb0 = ((const float4*)bias)[fl * 2];
    float4 bb1 = ((const float4*)bias)[fl * 2 + 1];
    float bbv[8] = {bb0.x, bb0.y, bb0.z, bb0.w, bb1.x, bb1.y, bb1.z, bb1.w};
    float* ar = acc[nl] + fl * 8;
#pragma unroll
    for (int i = 0; i < 8; ++i)
        ar[i] = fmaxf(fmaf(iv, ar[i] + sf[i], bbv[i]), 0.f);
    __syncthreads();
    // classifier: thread (nl, p=fl) computes classes 2p, 2p+1
    const float* rr = acc[nl];
    const float* w0 = WcT[2 * fl];
    const float* w1 = WcT[2 * fl + 1];
    float l0 = 0.f, l1 = 0.f;
#pragma unroll
    for (int i = 0; i < FDIM; ++i) {
        float xk = rr[i];
        l0 = fmaf(xk, w0[i], l0);
        l1 = fmaf(xk, w1[i], l1);
    }
    if (node < n) {
        float2 ov = make_float2(l0 + bc[2 * fl], l1 + bc[2 * fl + 1]);
        ((float2*)out)[(size_t)node * 8 + fl] = ov;
    }
}

static inline size_t align256(size_t x) { return (x + 255) & ~(size_t)255; }

extern "C" void kernel_launch(void* const* d_in, const int* in_sizes, int n_in,
                              void* d_out, int out_size, void* d_ws, size_t ws_size,
                              hipStream_t stream) {
    const float* x  = (const float*)d_in[0];
    const int*   ei = (const int*)d_in[1];
    const float* W1 = (const float*)d_in[2];
    const float* b1 = (const float*)d_in[3];
    const float* W2 = (const float*)d_in[4];
    const float* b2 = (const float*)d_in[5];
    const float* Wc = (const float*)d_in[6];
    const float* bc = (const float*)d_in[7];
    float* out = (float*)d_out;

    const int n = in_sizes[0] / FDIM;   // 50000
    const int E = in_sizes[1] / 2;      // 800000
    const int* src = ei;
    const int* dst = ei + E;

    const int nb = (n + 255) >> 8;            // 196 buckets
    const int nblk = (E + TILE - 1) / TILE;   // 391 tiles

    // workspace carve-up
    char* w = (char*)d_ws;
    size_t off = 0;
    int* H = (int*)(w + off);        off = align256(off + (size_t)nblk * 256 * 4);
    int* btot = (int*)(w + off);     off = align256(off + 256 * 4);
    int* row_ptr = (int*)(w + off);  off = align256(off + (size_t)(n + 1) * 4);
    float* inv = (float*)(w + off);  off = align256(off + (size_t)n * 4);
    unsigned* tmp = (unsigned*)(w + off);             off = align256(off + (size_t)E * 4);
    unsigned short* col = (unsigned short*)(w + off); off = align256(off + (size_t)(E + 8) * 2);
    __half* P1 = (__half*)(w + off); off = align256(off + (size_t)n * FDIM * 2);
    __half* P2 = (__half*)(w + off); off = align256(off + (size_t)n * FDIM * 2);
    (void)ws_size;

    const int nbG = (n * 4 + 255) / 256;
    const int nbE = (n + ANODE - 1) / ANODE;   // 782 agg blocks (64 nodes each)

    // CSR build + fused layer-1 GEMM riding along
    k_histgemm<<<nblk + nbG, 256, 0, stream>>>(dst, E, H, nblk, x, W1, P1, n);
    k_scanH<<<nb, 512, 0, stream>>>(H, nblk, btot);
    k_scatA<<<nblk, 256, 0, stream>>>(src, dst, E, H, btot, nb, tmp);
    k_binB<<<nb, 256, 0, stream>>>(tmp, btot, nb, n, E, row_ptr, inv, col);

    // edge-centric agg layer 1 (inv[src]-weighted) + fused W2 GEMM -> P2
    k_aggE1<<<nbE, 512, 0, stream>>>(P1, inv, row_ptr, col, b1, W2, P2, n);
    // edge-centric agg layer 2 + fused classifier
    k_aggE2<<<nbE, 512, 0, stream>>>(P2, inv, row_ptr, col, b2, Wc, bc, out, n);
}

// Round 5
// 173.625 us; speedup vs baseline: 4.6985x; 4.6985x over previous
//
#include <hip/hip_runtime.h>
#include <hip/hip_fp16.h>

// GCN 2-layer + classifier, fp32 math, fp16 message buffers.
// R13: back to R2 structure (156.8us measured; R11 pipeline and R12 LDS-atomic
//      rewrites both regressed). Single change: aggs get __launch_bounds__(256,6)
//      -> VGPR cap 85 -> 6 waves/SIMD (R3 counters: VALUBusy 15%, occ 8%,
//      VGPR 132 => ~3 waves/SIMD; chain ~1100cyc >> 3x350cyc issue => idle).
//      Register diet via SENTINEL tail: c[k]=n for tail edges, inv[n]=0,
//      P1/P2 have a zeroed row n => no per-edge compares, no wk[] in aggF2.
// R10: 8 lanes/node * uint4: one wave = 8 nodes, 0.375 VMEM/edge.
// R9: gemm1 fused into hist kernel. P1 UNSCALED h=X@W1; source-side norm
//     applied in aggF1 as gathered weight wk=inv[src]. P2 pre-scaled.
// CSR-by-dst rebuilt per launch via radix partition, ZERO global atomics.
// Requires n < 65536 (u16 col). Here n=50000, E=800000.

#define FDIM 64
#define NCLS 16
#define TILE 2048

// ---- partition pass 1: per-(tile,bucket) histogram + fused layer-1 GEMM ----
__global__ __launch_bounds__(256) void k_histgemm(const int* __restrict__ dst, int E,
                                                  int* __restrict__ H, int nblk,
                                                  const float* __restrict__ X,
                                                  const float* __restrict__ W,
                                                  __half* __restrict__ Yh, int n) {
    __shared__ float Ws[FDIM * FDIM];
    __shared__ int h[256];
    int t = threadIdx.x, blk = blockIdx.x;
    if (blk < nblk) {
        h[t] = 0;
        __syncthreads();
        int i0 = blk * TILE;
#pragma unroll
        for (int k = 0; k < TILE / 256; ++k) {
            int i = i0 + k * 256 + t;
            if (i < E) atomicAdd(&h[dst[i] >> 8], 1);
        }
        __syncthreads();
        H[blk * 256 + t] = h[t];   // coalesced
    } else {
        for (int i = t; i < FDIM * FDIM; i += 256) Ws[i] = W[i];
        __syncthreads();
        // zero sentinel row n of P1 (tail edges gather it with weight 0)
        if (blk == nblk && t < 8)
            ((uint4*)Yh)[(size_t)n * 8 + t] = make_uint4(0, 0, 0, 0);
        int idx = (blk - nblk) * 256 + t;
        int row = idx >> 2;
        int cg = (idx & 3) * 16;
        if (row >= n) return;
        const float4* xr = (const float4*)(X + (size_t)row * FDIM);
        float4 xv[16];
#pragma unroll
        for (int i = 0; i < 16; ++i) xv[i] = xr[i];
        float acc[16];
#pragma unroll
        for (int c = 0; c < 16; ++c) acc[c] = 0.f;
#pragma unroll
        for (int i = 0; i < 16; ++i) {
            float xs[4] = {xv[i].x, xv[i].y, xv[i].z, xv[i].w};
#pragma unroll
            for (int j = 0; j < 4; ++j) {
                float xk = xs[j];
                const float* wr = &Ws[(i * 4 + j) * FDIM + cg];
#pragma unroll
                for (int c = 0; c < 16; ++c) acc[c] += xk * wr[c];
            }
        }
        unsigned u[8];
#pragma unroll
        for (int i = 0; i < 8; ++i) {
            __half2 hp = __floats2half2_rn(acc[2 * i], acc[2 * i + 1]);
            u[i] = *(unsigned*)&hp;
        }
        uint4* yo = (uint4*)(Yh + (size_t)row * FDIM + cg);
        yo[0] = make_uint4(u[0], u[1], u[2], u[3]);
        yo[1] = make_uint4(u[4], u[5], u[6], u[7]);
    }
}

// ---- partition pass 2: per-bucket exclusive scan across tiles ----
__global__ __launch_bounds__(512) void k_scanH(int* __restrict__ H, int nblk, int* __restrict__ btot) {
    __shared__ int s[512];
    int t = threadIdx.x, b = blockIdx.x;
    int v = (t < nblk) ? H[t * 256 + b] : 0;
    s[t] = v;
    __syncthreads();
    for (int off = 1; off < 512; off <<= 1) {
        int add = (t >= off) ? s[t - off] : 0;
        __syncthreads();
        s[t] += add;
        __syncthreads();
    }
    if (t < nblk) H[t * 256 + b] = s[t] - v;  // exclusive within bucket
    if (t == 511) btot[b] = s[511];
}

// ---- partition pass 3: scatter packed records into bucket regions ----
__global__ __launch_bounds__(256) void k_scatA(const int* __restrict__ src, const int* __restrict__ dst,
                                               int E, const int* __restrict__ H,
                                               const int* __restrict__ btot, int nb,
                                               unsigned* __restrict__ tmp) {
    __shared__ int s[256];
    __shared__ int Hb[256];
    __shared__ int c2[256];
    int t = threadIdx.x, blk = blockIdx.x;
    int v = (t < nb) ? btot[t] : 0;
    s[t] = v;
    __syncthreads();
    for (int off = 1; off < 256; off <<= 1) {
        int add = (t >= off) ? s[t - off] : 0;
        __syncthreads();
        s[t] += add;
        __syncthreads();
    }
    Hb[t] = (s[t] - v) + H[blk * 256 + t];   // bucket base + tile offset
    c2[t] = 0;
    __syncthreads();
    int i0 = blk * TILE;
#pragma unroll
    for (int k = 0; k < TILE / 256; ++k) {
        int i = i0 + k * 256 + t;
        if (i < E) {
            int sv = src[i], d = dst[i];
            int b = d >> 8;
            unsigned rec = ((unsigned)(d & 255) << 16) | (unsigned)sv;
            int pos = Hb[b] + atomicAdd(&c2[b], 1);
            tmp[pos] = rec;
        }
    }
}

// ---- per-bucket CSR finalize: row_ptr, inv, coalesced u16 col ----
#define COLCAP 8192
__global__ __launch_bounds__(256) void k_binB(const unsigned* __restrict__ tmp,
                                              const int* __restrict__ btot, int nb,
                                              int n, int E, int* __restrict__ row_ptr,
                                              float* __restrict__ inv,
                                              unsigned short* __restrict__ col) {
    __shared__ int dcnt[256], s[256], cur[256];
    __shared__ unsigned short colbuf[COLCAP];
    int t = threadIdx.x, b = blockIdx.x;
    int v = (t < nb) ? btot[t] : 0;
    s[t] = v;
    __syncthreads();
    for (int off = 1; off < 256; off <<= 1) {
        int add = (t >= off) ? s[t - off] : 0;
        __syncthreads();
        s[t] += add;
        __syncthreads();
    }
    __shared__ int baseS;
    if (t == b) baseS = s[t] - v;
    dcnt[t] = 0;
    __syncthreads();
    int base = baseS;
    int cntE = btot[b];
    int node0 = b << 8;
    int nn = min(256, n - node0);
    for (int i = t; i < cntE; i += 256) atomicAdd(&dcnt[tmp[base + i] >> 16], 1);
    __syncthreads();
    int deg = dcnt[t];
    s[t] = deg;
    __syncthreads();
    for (int off = 1; off < 256; off <<= 1) {
        int add = (t >= off) ? s[t - off] : 0;
        __syncthreads();
        s[t] += add;
        __syncthreads();
    }
    int excl = s[t] - deg;
    if (t < nn) {
        row_ptr[node0 + t] = base + excl;
        inv[node0 + t] = rsqrtf((float)(deg + 1));
    }
    if (b == 0 && t == 0) { row_ptr[n] = E; inv[n] = 0.f; }   // sentinel weight
    cur[t] = excl;
    __syncthreads();
    for (int i = t; i < cntE; i += 256) {
        unsigned r = tmp[base + i];
        int pos = atomicAdd(&cur[r >> 16], 1);
        unsigned short vv = (unsigned short)(r & 0xFFFFu);
        if (pos < COLCAP) colbuf[pos] = vv;
        else col[base + pos] = vv;   // overflow fallback
    }
    __syncthreads();
    int lim = min(cntE, COLCAP);
    for (int i = t; i < lim; i += 256) col[base + i] = colbuf[i];
}

__device__ __forceinline__ void unpack8(const uint4& q, float* f) {
    float2 f0 = __half22float2(*(const __half2*)&q.x);
    float2 f1 = __half22float2(*(const __half2*)&q.y);
    float2 f2 = __half22float2(*(const __half2*)&q.z);
    float2 f3 = __half22float2(*(const __half2*)&q.w);
    f[0] = f0.x; f[1] = f0.y; f[2] = f1.x; f[3] = f1.y;
    f[4] = f2.x; f[5] = f2.y; f[6] = f3.x; f[7] = f3.y;
}

// ---- agg layer 1 (inv[src]-weighted) + fused W2 GEMM -> P2 (fp16) ----
// Phase A: 8 nodes/wave, 8 lanes x 8 halfs (uint4); 32 nodes/block.
// Tail edges -> sentinel row n (inv[n]=0, P1 row n zeroed): no compares.
// Phase B: 256 threads = 32 nodes x 8 col-octets; P2 = fp16(inv * (r @ W2)).
__global__ __launch_bounds__(256, 6) void k_aggF1(const __half* __restrict__ Ph, const float* __restrict__ inv,
                                                  const int* __restrict__ row_ptr,
                                                  const unsigned short* __restrict__ col,
                                                  const float* __restrict__ bias,
                                                  const float* __restrict__ W2,
                                                  __half* __restrict__ P2, int n) {
    __shared__ float W2s[FDIM * FDIM];
    __shared__ float rbuf[32][FDIM + 1];
    int t0 = threadIdx.x;
    for (int i = t0; i < FDIM * FDIM; i += 256) W2s[i] = W2[i];
    // zero sentinel row n of P2 for aggF2 (weight-free tail there)
    if (blockIdx.x == 0 && t0 < 8)
        ((uint4*)P2)[(size_t)n * 8 + t0] = make_uint4(0, 0, 0, 0);
    int lane = t0 & 63;
    int sub = lane >> 3;      // node-in-wave 0..7
    int fl = lane & 7;        // feature octet 0..7
    int wid = t0 >> 6;
    int nl = wid * 8 + sub;   // local node 0..31
    int node = blockIdx.x * 32 + nl;
    bool alive = node < n;
    int nodeC = alive ? node : (n - 1);
    float iv = inv[nodeC];
    const uint4* Pq = (const uint4*)Ph;
    uint4 selfq = Pq[(size_t)nodeC * 8 + fl];
    float a[8], f[8];
    unpack8(selfq, f);
#pragma unroll
    for (int i = 0; i < 8; ++i) a[i] = iv * f[i];   // self term: inv[d]*h[d]
    int s = row_ptr[nodeC];
    int e = alive ? row_ptr[nodeC + 1] : s;
    for (int j = s; j < e; j += 8) {
        int c[8];
        float wk[8];
        uint4 q[8];
#pragma unroll
        for (int k = 0; k < 8; ++k) {
            int jj = j + k;
            c[k] = (jj < e) ? (int)col[jj] : n;   // sentinel
        }
#pragma unroll
        for (int k = 0; k < 8; ++k) wk[k] = inv[c[k]];   // inv[n]=0 kills tail
#pragma unroll
        for (int k = 0; k < 8; ++k) q[k] = Pq[(size_t)c[k] * 8 + fl];
#pragma unroll
        for (int k = 0; k < 8; ++k) {
            unpack8(q[k], f);
#pragma unroll
            for (int i = 0; i < 8; ++i) a[i] = fmaf(wk[k], f[i], a[i]);
        }
    }
    float4 bb0 = ((const float4*)bias)[fl * 2];
    float4 bb1 = ((const float4*)bias)[fl * 2 + 1];
    float bbv[8] = {bb0.x, bb0.y, bb0.z, bb0.w, bb1.x, bb1.y, bb1.z, bb1.w};
#pragma unroll
    for (int i = 0; i < 8; ++i)
        rbuf[nl][fl * 8 + i] = fmaxf(fmaf(iv, a[i], bbv[i]), 0.f);
    __syncthreads();   // covers W2s load too
    // Phase B: 256 threads = 32 nodes x 8 col-octets
    int nl2 = t0 >> 3;
    int cg = t0 & 7;
    int node2 = blockIdx.x * 32 + nl2;
    const float* rr = rbuf[nl2];
    float o[8];
#pragma unroll
    for (int i = 0; i < 8; ++i) o[i] = 0.f;
#pragma unroll
    for (int i = 0; i < FDIM; ++i) {
        float xk = rr[i];
        const float* wv = &W2s[i * FDIM + cg * 8];
#pragma unroll
        for (int c = 0; c < 8; ++c) o[c] = fmaf(xk, wv[c], o[c]);
    }
    if (node2 < n) {
        float iv2 = inv[node2];
        unsigned u[4];
#pragma unroll
        for (int i = 0; i < 4; ++i) {
            __half2 hp = __floats2half2_rn(o[2 * i] * iv2, o[2 * i + 1] * iv2);
            u[i] = *(unsigned*)&hp;
        }
        ((uint4*)P2)[(size_t)node2 * 8 + cg] = make_uint4(u[0], u[1], u[2], u[3]);
    }
}

// ---- agg layer 2 + fused classifier (P2 pre-scaled -> weight-free) ----
// Tail edges -> sentinel row n of P2 (zeroed) -> unconditional adds, no wk[].
__global__ __launch_bounds__(256, 6) void k_aggF2(const __half* __restrict__ Ph, const float* __restrict__ inv,
                                                  const int* __restrict__ row_ptr,
                                                  const unsigned short* __restrict__ col,
                                                  const float* __restrict__ bias,
                                                  const float* __restrict__ Wc, const float* __restrict__ bc,
                                                  float* __restrict__ out, int n) {
    __shared__ float WcT[NCLS * FDIM];   // transposed: WcT[c*64+f]
    int t0 = threadIdx.x;
    for (int i = t0; i < FDIM * NCLS; i += 256) {
        int c = i & 15, ff = i >> 4;
        WcT[c * FDIM + ff] = Wc[i];
    }
    __syncthreads();
    int lane = t0 & 63;
    int sub = lane >> 3;
    int fl = lane & 7;
    int wid = t0 >> 6;
    int node = blockIdx.x * 32 + wid * 8 + sub;
    bool alive = node < n;
    int nodeC = alive ? node : (n - 1);
    float iv = inv[nodeC];
    const uint4* Pq = (const uint4*)Ph;
    uint4 selfq = Pq[(size_t)nodeC * 8 + fl];
    float a[8], f[8];
    unpack8(selfq, a);
    int s = row_ptr[nodeC];
    int e = alive ? row_ptr[nodeC + 1] : s;
    for (int j = s; j < e; j += 8) {
        int c[8];
        uint4 q[8];
#pragma unroll
        for (int k = 0; k < 8; ++k) {
            int jj = j + k;
            c[k] = (jj < e) ? (int)col[jj] : n;   // sentinel row is zeros
        }
#pragma unroll
        for (int k = 0; k < 8; ++k) q[k] = Pq[(size_t)c[k] * 8 + fl];
#pragma unroll
        for (int k = 0; k < 8; ++k) {
            unpack8(q[k], f);
#pragma unroll
            for (int i = 0; i < 8; ++i) a[i] += f[i];
        }
    }
    float4 bb0 = ((const float4*)bias)[fl * 2];
    float4 bb1 = ((const float4*)bias)[fl * 2 + 1];
    float bbv[8] = {bb0.x, bb0.y, bb0.z, bb0.w, bb1.x, bb1.y, bb1.z, bb1.w};
    float r[8];
#pragma unroll
    for (int i = 0; i < 8; ++i) r[i] = fmaxf(fmaf(iv, a[i], bbv[i]), 0.f);
    float part[NCLS];
#pragma unroll
    for (int c = 0; c < NCLS; ++c) {
        float4 wv0 = ((const float4*)(WcT + c * FDIM))[fl * 2];
        float4 wv1 = ((const float4*)(WcT + c * FDIM))[fl * 2 + 1];
        part[c] = r[0] * wv0.x;
        part[c] = fmaf(r[1], wv0.y, part[c]);
        part[c] = fmaf(r[2], wv0.z, part[c]);
        part[c] = fmaf(r[3], wv0.w, part[c]);
        part[c] = fmaf(r[4], wv1.x, part[c]);
        part[c] = fmaf(r[5], wv1.y, part[c]);
        part[c] = fmaf(r[6], wv1.z, part[c]);
        part[c] = fmaf(r[7], wv1.w, part[c]);
    }
#pragma unroll
    for (int m = 1; m < 8; m <<= 1) {
#pragma unroll
        for (int c = 0; c < NCLS; ++c) part[c] += __shfl_xor(part[c], m, 64);
    }
    if (alive && fl < 4) {
        float4 bb2 = ((const float4*)bc)[fl];
        float4 o = make_float4(part[fl * 4 + 0] + bb2.x, part[fl * 4 + 1] + bb2.y,
                               part[fl * 4 + 2] + bb2.z, part[fl * 4 + 3] + bb2.w);
        ((float4*)out)[(size_t)node * 4 + fl] = o;
    }
}

static inline size_t align256(size_t x) { return (x + 255) & ~(size_t)255; }

extern "C" void kernel_launch(void* const* d_in, const int* in_sizes, int n_in,
                              void* d_out, int out_size, void* d_ws, size_t ws_size,
                              hipStream_t stream) {
    const float* x  = (const float*)d_in[0];
    const int*   ei = (const int*)d_in[1];
    const float* W1 = (const float*)d_in[2];
    const float* b1 = (const float*)d_in[3];
    const float* W2 = (const float*)d_in[4];
    const float* b2 = (const float*)d_in[5];
    const float* Wc = (const float*)d_in[6];
    const float* bc = (const float*)d_in[7];
    float* out = (float*)d_out;

    const int n = in_sizes[0] / FDIM;   // 50000
    const int E = in_sizes[1] / 2;      // 800000
    const int* src = ei;
    const int* dst = ei + E;

    const int nb = (n + 255) >> 8;            // 196 buckets
    const int nblk = (E + TILE - 1) / TILE;   // 391 tiles

    // workspace carve-up (P1/P2/inv have +1 sentinel row/entry)
    char* w = (char*)d_ws;
    size_t off = 0;
    int* H = (int*)(w + off);        off = align256(off + (size_t)nblk * 256 * 4);
    int* btot = (int*)(w + off);     off = align256(off + 256 * 4);
    int* row_ptr = (int*)(w + off);  off = align256(off + (size_t)(n + 1) * 4);
    float* inv = (float*)(w + off);  off = align256(off + (size_t)(n + 1) * 4);
    unsigned* tmp = (unsigned*)(w + off);             off = align256(off + (size_t)E * 4);
    unsigned short* col = (unsigned short*)(w + off); off = align256(off + (size_t)(E + 8) * 2);
    __half* P1 = (__half*)(w + off); off = align256(off + (size_t)(n + 1) * FDIM * 2);
    __half* P2 = (__half*)(w + off); off = align256(off + (size_t)(n + 1) * FDIM * 2);
    (void)ws_size;

    const int nbG = (n * 4 + 255) / 256;
    const int nbA = (n + 31) / 32;     // 32 nodes per block

    // CSR build + fused layer-1 GEMM riding along
    k_histgemm<<<nblk + nbG, 256, 0, stream>>>(dst, E, H, nblk, x, W1, P1, n);
    k_scanH<<<nb, 512, 0, stream>>>(H, nblk, btot);
    k_scatA<<<nblk, 256, 0, stream>>>(src, dst, E, H, btot, nb, tmp);
    k_binB<<<nb, 256, 0, stream>>>(tmp, btot, nb, n, E, row_ptr, inv, col);

    // layer 1 agg (inv[src]-weighted) + fused layer 2 GEMM -> P2 (pre-scaled)
    k_aggF1<<<nbA, 256, 0, stream>>>(P1, inv, row_ptr, col, b1, W2, P2, n);
    // layer 2 agg + fused classifier
    k_aggF2<<<nbA, 256, 0, stream>>>(P2, inv, row_ptr, col, b2, Wc, bc, out, n);
}

// Round 6
// 163.146 us; speedup vs baseline: 5.0002x; 1.0642x over previous
//
#include <hip/hip_runtime.h>
#include <hip/hip_fp16.h>

// GCN 2-layer + classifier, fp32 math, fp16 message buffers.
// R14: DEGREE-SORTED node processing. Aggs are latency-chain bound; chain
//      iterations/wave = max over 8 wave-nodes of ceil(deg/8). Poisson(16):
//      E[max of 8]~26 -> 4 chunks vs E[ceil(deg/8)]~2.3. binB counting-sorts
//      each 256-node bucket by degree (LDS hist+scan, no extra launch) ->
//      perm; agg waves draw 8 consecutive perm entries = near-uniform deg.
//      Per-node arithmetic UNCHANGED -> bit-identical output.
// R13 REVERTED (VGPR cap -> spills; 8-edge chunk needs ~130 VGPR).
// R11/R12 REVERTED (src pipeline + LDS atomics both regressed).
// R10: 8 lanes/node * uint4: one wave = 8 nodes, 0.375 VMEM/edge.
// R9: gemm1 fused into hist kernel. P1 UNSCALED h=X@W1; source-side norm
//     applied in aggF1 as gathered weight wk=inv[src]. P2 pre-scaled.
// CSR-by-dst rebuilt per launch via radix partition, ZERO global atomics.
// Requires n < 65536 (u16 col). Here n=50000, E=800000.

#define FDIM 64
#define NCLS 16
#define TILE 2048

// ---- partition pass 1: per-(tile,bucket) histogram + fused layer-1 GEMM ----
__global__ __launch_bounds__(256) void k_histgemm(const int* __restrict__ dst, int E,
                                                  int* __restrict__ H, int nblk,
                                                  const float* __restrict__ X,
                                                  const float* __restrict__ W,
                                                  __half* __restrict__ Yh, int n) {
    __shared__ float Ws[FDIM * FDIM];
    __shared__ int h[256];
    int t = threadIdx.x, blk = blockIdx.x;
    if (blk < nblk) {
        h[t] = 0;
        __syncthreads();
        int i0 = blk * TILE;
#pragma unroll
        for (int k = 0; k < TILE / 256; ++k) {
            int i = i0 + k * 256 + t;
            if (i < E) atomicAdd(&h[dst[i] >> 8], 1);
        }
        __syncthreads();
        H[blk * 256 + t] = h[t];   // coalesced
    } else {
        for (int i = t; i < FDIM * FDIM; i += 256) Ws[i] = W[i];
        __syncthreads();
        int idx = (blk - nblk) * 256 + t;
        int row = idx >> 2;
        int cg = (idx & 3) * 16;
        if (row >= n) return;
        const float4* xr = (const float4*)(X + (size_t)row * FDIM);
        float4 xv[16];
#pragma unroll
        for (int i = 0; i < 16; ++i) xv[i] = xr[i];
        float acc[16];
#pragma unroll
        for (int c = 0; c < 16; ++c) acc[c] = 0.f;
#pragma unroll
        for (int i = 0; i < 16; ++i) {
            float xs[4] = {xv[i].x, xv[i].y, xv[i].z, xv[i].w};
#pragma unroll
            for (int j = 0; j < 4; ++j) {
                float xk = xs[j];
                const float* wr = &Ws[(i * 4 + j) * FDIM + cg];
#pragma unroll
                for (int c = 0; c < 16; ++c) acc[c] += xk * wr[c];
            }
        }
        unsigned u[8];
#pragma unroll
        for (int i = 0; i < 8; ++i) {
            __half2 hp = __floats2half2_rn(acc[2 * i], acc[2 * i + 1]);
            u[i] = *(unsigned*)&hp;
        }
        uint4* yo = (uint4*)(Yh + (size_t)row * FDIM + cg);
        yo[0] = make_uint4(u[0], u[1], u[2], u[3]);
        yo[1] = make_uint4(u[4], u[5], u[6], u[7]);
    }
}

// ---- partition pass 2: per-bucket exclusive scan across tiles ----
__global__ __launch_bounds__(512) void k_scanH(int* __restrict__ H, int nblk, int* __restrict__ btot) {
    __shared__ int s[512];
    int t = threadIdx.x, b = blockIdx.x;
    int v = (t < nblk) ? H[t * 256 + b] : 0;
    s[t] = v;
    __syncthreads();
    for (int off = 1; off < 512; off <<= 1) {
        int add = (t >= off) ? s[t - off] : 0;
        __syncthreads();
        s[t] += add;
        __syncthreads();
    }
    if (t < nblk) H[t * 256 + b] = s[t] - v;  // exclusive within bucket
    if (t == 511) btot[b] = s[511];
}

// ---- partition pass 3: scatter packed records into bucket regions ----
__global__ __launch_bounds__(256) void k_scatA(const int* __restrict__ src, const int* __restrict__ dst,
                                               int E, const int* __restrict__ H,
                                               const int* __restrict__ btot, int nb,
                                               unsigned* __restrict__ tmp) {
    __shared__ int s[256];
    __shared__ int Hb[256];
    __shared__ int c2[256];
    int t = threadIdx.x, blk = blockIdx.x;
    int v = (t < nb) ? btot[t] : 0;
    s[t] = v;
    __syncthreads();
    for (int off = 1; off < 256; off <<= 1) {
        int add = (t >= off) ? s[t - off] : 0;
        __syncthreads();
        s[t] += add;
        __syncthreads();
    }
    Hb[t] = (s[t] - v) + H[blk * 256 + t];   // bucket base + tile offset
    c2[t] = 0;
    __syncthreads();
    int i0 = blk * TILE;
#pragma unroll
    for (int k = 0; k < TILE / 256; ++k) {
        int i = i0 + k * 256 + t;
        if (i < E) {
            int sv = src[i], d = dst[i];
            int b = d >> 8;
            unsigned rec = ((unsigned)(d & 255) << 16) | (unsigned)sv;
            int pos = Hb[b] + atomicAdd(&c2[b], 1);
            tmp[pos] = rec;
        }
    }
}

// ---- per-bucket CSR finalize: row_ptr, inv, u16 col + degree-sort perm ----
#define COLCAP 8192
__global__ __launch_bounds__(256) void k_binB(const unsigned* __restrict__ tmp,
                                              const int* __restrict__ btot, int nb,
                                              int n, int E, int* __restrict__ row_ptr,
                                              float* __restrict__ inv,
                                              unsigned short* __restrict__ col,
                                              int* __restrict__ perm) {
    __shared__ int dcnt[256], s[256], cur[256];
    __shared__ unsigned short colbuf[COLCAP];
    int t = threadIdx.x, b = blockIdx.x;
    int v = (t < nb) ? btot[t] : 0;
    s[t] = v;
    __syncthreads();
    for (int off = 1; off < 256; off <<= 1) {
        int add = (t >= off) ? s[t - off] : 0;
        __syncthreads();
        s[t] += add;
        __syncthreads();
    }
    __shared__ int baseS;
    if (t == b) baseS = s[t] - v;
    dcnt[t] = 0;
    __syncthreads();
    int base = baseS;
    int cntE = btot[b];
    int node0 = b << 8;
    int nn = min(256, n - node0);
    for (int i = t; i < cntE; i += 256) atomicAdd(&dcnt[tmp[base + i] >> 16], 1);
    __syncthreads();
    int deg = dcnt[t];
    s[t] = deg;
    __syncthreads();
    for (int off = 1; off < 256; off <<= 1) {
        int add = (t >= off) ? s[t - off] : 0;
        __syncthreads();
        s[t] += add;
        __syncthreads();
    }
    int excl = s[t] - deg;
    if (t < nn) {
        row_ptr[node0 + t] = base + excl;
        inv[node0 + t] = rsqrtf((float)(deg + 1));
    }
    if (b == 0 && t == 0) row_ptr[n] = E;
    cur[t] = excl;
    __syncthreads();
    for (int i = t; i < cntE; i += 256) {
        unsigned r = tmp[base + i];
        int pos = atomicAdd(&cur[r >> 16], 1);
        unsigned short vv = (unsigned short)(r & 0xFFFFu);
        if (pos < COLCAP) colbuf[pos] = vv;
        else col[base + pos] = vv;   // overflow fallback
    }
    __syncthreads();
    int lim = min(cntE, COLCAP);
    for (int i = t; i < lim; i += 256) col[base + i] = colbuf[i];
    // ---- counting-sort this bucket's nodes by degree -> perm ----
    // (agg waves then draw 8 near-equal-degree nodes: chain iters/wave
    //  drop from max-of-8 ~4 chunks to ~2.4)
    __syncthreads();
    s[t] = 0;
    __syncthreads();
    int dg = min(deg, 255);
    if (t < nn) atomicAdd(&s[dg], 1);
    __syncthreads();
    int hv = s[t];
    __syncthreads();
    for (int off = 1; off < 256; off <<= 1) {
        int add = (t >= off) ? s[t - off] : 0;
        __syncthreads();
        s[t] += add;
        __syncthreads();
    }
    cur[t] = s[t] - hv;   // exclusive base per degree class
    __syncthreads();
    if (t < nn) {
        int rk = atomicAdd(&cur[dg], 1);
        perm[node0 + rk] = node0 + t;
    }
}

__device__ __forceinline__ void unpack8(const uint4& q, float* f) {
    float2 f0 = __half22float2(*(const __half2*)&q.x);
    float2 f1 = __half22float2(*(const __half2*)&q.y);
    float2 f2 = __half22float2(*(const __half2*)&q.z);
    float2 f3 = __half22float2(*(const __half2*)&q.w);
    f[0] = f0.x; f[1] = f0.y; f[2] = f1.x; f[3] = f1.y;
    f[4] = f2.x; f[5] = f2.y; f[6] = f3.x; f[7] = f3.y;
}

// ---- agg layer 1 (inv[src]-weighted) + fused W2 GEMM -> P2 (fp16) ----
// Phase A: 8 nodes/wave (degree-sorted via perm), 8 lanes x 8 halfs (uint4).
// Phase B: 256 threads = 32 nodes x 8 col-octets; P2 = fp16(inv * (r @ W2)).
__global__ __launch_bounds__(256) void k_aggF1(const __half* __restrict__ Ph, const float* __restrict__ inv,
                                               const int* __restrict__ row_ptr,
                                               const unsigned short* __restrict__ col,
                                               const int* __restrict__ perm,
                                               const float* __restrict__ bias,
                                               const float* __restrict__ W2,
                                               __half* __restrict__ P2, int n) {
    __shared__ float W2s[FDIM * FDIM];
    __shared__ float rbuf[32][FDIM + 1];
    int t0 = threadIdx.x;
    for (int i = t0; i < FDIM * FDIM; i += 256) W2s[i] = W2[i];
    int lane = t0 & 63;
    int sub = lane >> 3;      // node-in-wave 0..7
    int fl = lane & 7;        // feature octet 0..7
    int wid = t0 >> 6;
    int nl = wid * 8 + sub;   // local node 0..31
    int idx = blockIdx.x * 32 + nl;
    bool alive = idx < n;
    int nodeC = perm[alive ? idx : (n - 1)];
    float iv = inv[nodeC];
    const uint4* Pq = (const uint4*)Ph;
    uint4 selfq = Pq[(size_t)nodeC * 8 + fl];
    float a[8], f[8];
    unpack8(selfq, f);
#pragma unroll
    for (int i = 0; i < 8; ++i) a[i] = iv * f[i];   // self term: inv[d]*h[d]
    int s = row_ptr[nodeC];
    int e = alive ? row_ptr[nodeC + 1] : s;
    for (int j = s; j < e; j += 8) {
        int c[8];
        float wk[8];
        uint4 q[8];
#pragma unroll
        for (int k = 0; k < 8; ++k) {
            int jj = j + k;
            c[k] = col[jj < e ? jj : s];
        }
#pragma unroll
        for (int k = 0; k < 8; ++k) wk[k] = ((j + k) < e) ? inv[c[k]] : 0.f;
#pragma unroll
        for (int k = 0; k < 8; ++k) q[k] = Pq[(size_t)c[k] * 8 + fl];
#pragma unroll
        for (int k = 0; k < 8; ++k) {
            unpack8(q[k], f);
#pragma unroll
            for (int i = 0; i < 8; ++i) a[i] = fmaf(wk[k], f[i], a[i]);
        }
    }
    float4 bb0 = ((const float4*)bias)[fl * 2];
    float4 bb1 = ((const float4*)bias)[fl * 2 + 1];
    float bbv[8] = {bb0.x, bb0.y, bb0.z, bb0.w, bb1.x, bb1.y, bb1.z, bb1.w};
#pragma unroll
    for (int i = 0; i < 8; ++i)
        rbuf[nl][fl * 8 + i] = fmaxf(fmaf(iv, a[i], bbv[i]), 0.f);
    __syncthreads();   // covers W2s load too
    // Phase B: 256 threads = 32 nodes x 8 col-octets
    int nl2 = t0 >> 3;
    int cg = t0 & 7;
    int idx2 = blockIdx.x * 32 + nl2;
    const float* rr = rbuf[nl2];
    float o[8];
#pragma unroll
    for (int i = 0; i < 8; ++i) o[i] = 0.f;
#pragma unroll
    for (int i = 0; i < FDIM; ++i) {
        float xk = rr[i];
        const float* wv = &W2s[i * FDIM + cg * 8];
#pragma unroll
        for (int c = 0; c < 8; ++c) o[c] = fmaf(xk, wv[c], o[c]);
    }
    if (idx2 < n) {
        int node2 = perm[idx2];
        float iv2 = inv[node2];
        unsigned u[4];
#pragma unroll
        for (int i = 0; i < 4; ++i) {
            __half2 hp = __floats2half2_rn(o[2 * i] * iv2, o[2 * i + 1] * iv2);
            u[i] = *(unsigned*)&hp;
        }
        ((uint4*)P2)[(size_t)node2 * 8 + cg] = make_uint4(u[0], u[1], u[2], u[3]);
    }
}

// ---- agg layer 2 + fused classifier (P2 pre-scaled -> weight-free) ----
__global__ __launch_bounds__(256) void k_aggF2(const __half* __restrict__ Ph, const float* __restrict__ inv,
                                               const int* __restrict__ row_ptr,
                                               const unsigned short* __restrict__ col,
                                               const int* __restrict__ perm,
                                               const float* __restrict__ bias,
                                               const float* __restrict__ Wc, const float* __restrict__ bc,
                                               float* __restrict__ out, int n) {
    __shared__ float WcT[NCLS * FDIM];   // transposed: WcT[c*64+f]
    int t0 = threadIdx.x;
    for (int i = t0; i < FDIM * NCLS; i += 256) {
        int c = i & 15, ff = i >> 4;
        WcT[c * FDIM + ff] = Wc[i];
    }
    __syncthreads();
    int lane = t0 & 63;
    int sub = lane >> 3;
    int fl = lane & 7;
    int wid = t0 >> 6;
    int idx = blockIdx.x * 32 + wid * 8 + sub;
    bool alive = idx < n;
    int node = perm[alive ? idx : (n - 1)];
    float iv = inv[node];
    const uint4* Pq = (const uint4*)Ph;
    uint4 selfq = Pq[(size_t)node * 8 + fl];
    float a[8], f[8];
    unpack8(selfq, a);
    int s = row_ptr[node];
    int e = alive ? row_ptr[node + 1] : s;
    for (int j = s; j < e; j += 8) {
        int c[8];
        float wk[8];
        uint4 q[8];
#pragma unroll
        for (int k = 0; k < 8; ++k) {
            int jj = j + k;
            c[k] = col[jj < e ? jj : s];
            wk[k] = (jj < e) ? 1.f : 0.f;
        }
#pragma unroll
        for (int k = 0; k < 8; ++k) q[k] = Pq[(size_t)c[k] * 8 + fl];
#pragma unroll
        for (int k = 0; k < 8; ++k) {
            unpack8(q[k], f);
#pragma unroll
            for (int i = 0; i < 8; ++i) a[i] = fmaf(wk[k], f[i], a[i]);
        }
    }
    float4 bb0 = ((const float4*)bias)[fl * 2];
    float4 bb1 = ((const float4*)bias)[fl * 2 + 1];
    float bbv[8] = {bb0.x, bb0.y, bb0.z, bb0.w, bb1.x, bb1.y, bb1.z, bb1.w};
    float r[8];
#pragma unroll
    for (int i = 0; i < 8; ++i) r[i] = fmaxf(fmaf(iv, a[i], bbv[i]), 0.f);
    float part[NCLS];
#pragma unroll
    for (int c = 0; c < NCLS; ++c) {
        float4 wv0 = ((const float4*)(WcT + c * FDIM))[fl * 2];
        float4 wv1 = ((const float4*)(WcT + c * FDIM))[fl * 2 + 1];
        part[c] = r[0] * wv0.x;
        part[c] = fmaf(r[1], wv0.y, part[c]);
        part[c] = fmaf(r[2], wv0.z, part[c]);
        part[c] = fmaf(r[3], wv0.w, part[c]);
        part[c] = fmaf(r[4], wv1.x, part[c]);
        part[c] = fmaf(r[5], wv1.y, part[c]);
        part[c] = fmaf(r[6], wv1.z, part[c]);
        part[c] = fmaf(r[7], wv1.w, part[c]);
    }
#pragma unroll
    for (int m = 1; m < 8; m <<= 1) {
#pragma unroll
        for (int c = 0; c < NCLS; ++c) part[c] += __shfl_xor(part[c], m, 64);
    }
    if (alive && fl < 4) {
        float4 bb2 = ((const float4*)bc)[fl];
        float4 o = make_float4(part[fl * 4 + 0] + bb2.x, part[fl * 4 + 1] + bb2.y,
                               part[fl * 4 + 2] + bb2.z, part[fl * 4 + 3] + bb2.w);
        ((float4*)out)[(size_t)node * 4 + fl] = o;
    }
}

static inline size_t align256(size_t x) { return (x + 255) & ~(size_t)255; }

extern "C" void kernel_launch(void* const* d_in, const int* in_sizes, int n_in,
                              void* d_out, int out_size, void* d_ws, size_t ws_size,
                              hipStream_t stream) {
    const float* x  = (const float*)d_in[0];
    const int*   ei = (const int*)d_in[1];
    const float* W1 = (const float*)d_in[2];
    const float* b1 = (const float*)d_in[3];
    const float* W2 = (const float*)d_in[4];
    const float* b2 = (const float*)d_in[5];
    const float* Wc = (const float*)d_in[6];
    const float* bc = (const float*)d_in[7];
    float* out = (float*)d_out;

    const int n = in_sizes[0] / FDIM;   // 50000
    const int E = in_sizes[1] / 2;      // 800000
    const int* src = ei;
    const int* dst = ei + E;

    const int nb = (n + 255) >> 8;            // 196 buckets
    const int nblk = (E + TILE - 1) / TILE;   // 391 tiles

    // workspace carve-up
    char* w = (char*)d_ws;
    size_t off = 0;
    int* H = (int*)(w + off);        off = align256(off + (size_t)nblk * 256 * 4);
    int* btot = (int*)(w + off);     off = align256(off + 256 * 4);
    int* row_ptr = (int*)(w + off);  off = align256(off + (size_t)(n + 1) * 4);
    float* inv = (float*)(w + off);  off = align256(off + (size_t)n * 4);
    int* perm = (int*)(w + off);     off = align256(off + (size_t)n * 4);
    unsigned* tmp = (unsigned*)(w + off);             off = align256(off + (size_t)E * 4);
    unsigned short* col = (unsigned short*)(w + off); off = align256(off + (size_t)(E + 8) * 2);
    __half* P1 = (__half*)(w + off); off = align256(off + (size_t)n * FDIM * 2);
    __half* P2 = (__half*)(w + off); off = align256(off + (size_t)n * FDIM * 2);
    (void)ws_size;

    const int nbG = (n * 4 + 255) / 256;
    const int nbA = (n + 31) / 32;     // 32 nodes per block

    // CSR build + fused layer-1 GEMM riding along
    k_histgemm<<<nblk + nbG, 256, 0, stream>>>(dst, E, H, nblk, x, W1, P1, n);
    k_scanH<<<nb, 512, 0, stream>>>(H, nblk, btot);
    k_scatA<<<nblk, 256, 0, stream>>>(src, dst, E, H, btot, nb, tmp);
    k_binB<<<nb, 256, 0, stream>>>(tmp, btot, nb, n, E, row_ptr, inv, col, perm);

    // layer 1 agg (inv[src]-weighted, degree-sorted) + fused W2 GEMM -> P2
    k_aggF1<<<nbA, 256, 0, stream>>>(P1, inv, row_ptr, col, perm, b1, W2, P2, n);
    // layer 2 agg (degree-sorted) + fused classifier
    k_aggF2<<<nbA, 256, 0, stream>>>(P2, inv, row_ptr, col, perm, b2, Wc, bc, out, n);
}